// Round 9
// baseline (1247.577 us; speedup 1.0000x reference)
//
#include <hip/hip_runtime.h>
#include <stdint.h>

// ---------------------------------------------------------------------------
// RNNClassifier pipeline for MI355X (gfx950). Dtype-agnostic input handling
// (sniffer + converter to bf16). Core pipeline (MFMA, f32 accum):
//  k_prep : conv/w_ih weights -> bf16 MFMA B-frags; w_hh -> fp8 e4m3 MX
//           B-frags (16x16x128 layout) scaled x16; zero carries.
//  k_conv : embedding gather + (conv3|conv5) as one K=640 im2col GEMM -> y
//  k_bn   : finalize BN scale/shift
//  k_gx   : gx = ReLU(BN(y)) @ w_ih^T + b_ih + b_hh, TRUE scale, written as
//           8KB slabs per (t, 4-row group) [nt][c16][r] bf16
//  k_lstm : v12 = v8c + ASYMMETRIC wave priority. v8c step profile:
//           3880 cyc/SIMD = 2130 MFMA (both waves' clusters interleaved by
//           round-robin issue) + 1550 VALU (2 waves serialized on the one
//           VALU pipe) + sync. v11's symmetric setprio failed because BOTH
//           waves raised prio -> no differentiation. v12: only ODD waves
//           raise prio around the MFMA cluster -> odd drains its 32 MFMAs
//           first, then its gate VALU runs UNDER the even wave's MFMAs.
//           Value-identical (s_setprio is pure scheduling, wave-uniform).
//           Everything else byte-identical to v8c (207us/launch verified).
//  k_attn : attn/attn_out/logits epilogue
//  Launcher: if ws_size allows a 256MB gxb, run ONE k_gx (512 t) + ONE
//           k_lstm (512 steps); byte-identical 4-chunk fallback otherwise.
//
// MFMA 16x16x32 layouts (bf16 verified m89/m120):
//   A: lane holds A[m=lane&15][k=(lane>>4)*8+j], j=0..7
//   B: lane holds B[k=(lane>>4)*8+j][n=lane&15]
//   C/D: lane holds D[m=(lane>>4)*4+r][n=lane&15], r=0..3
// MX 16x16x128 f8f6f4 (natural 4x K extension, A/B symmetric k-map):
//   A: lane holds A[m=lane&15][k=(lane>>4)*32+j], j=0..31; B mirrored.
//   One e8m0 scale byte per 32-block; bytes replicated in the i32 scale
//   operand -> opsel-immune.
// ---------------------------------------------------------------------------

typedef __bf16 bf16x8 __attribute__((ext_vector_type(8)));
typedef float  f32x4  __attribute__((ext_vector_type(4)));
typedef int    i32x8  __attribute__((ext_vector_type(8)));

__device__ __forceinline__ float bf2f(uint16_t h){
  union { uint32_t u; float f; } v; v.u = ((uint32_t)h) << 16; return v.f;
}
__device__ __forceinline__ uint16_t f2bf(float f){
  union { float f; uint32_t u; } v; v.f = f;
  return (uint16_t)((v.u + 0x7FFFu + ((v.u >> 16) & 1u)) >> 16);
}
__device__ __forceinline__ bf16x8 ld_frag(const uint16_t* p){
  union { int4 i; bf16x8 b; } u; u.i = *(const int4*)p; return u.b;
}
__device__ __forceinline__ f32x4 mfma16(bf16x8 a, bf16x8 b, f32x4 c){
  return __builtin_amdgcn_mfma_f32_16x16x32_bf16(a, b, c, 0, 0, 0);
}
__device__ __forceinline__ float sigm(float x){
  return __builtin_amdgcn_rcpf(1.f + __expf(-x));
}
__device__ __forceinline__ float tanh_(float x){
  return 2.f * __builtin_amdgcn_rcpf(1.f + __expf(-2.f * x)) - 1.f;
}

// MX MFMA: imm args must be literal at the builtin callsite -> macro.
// scales: e8m0 bytes replicated; 0x7B = 2^-4, 0x77 = 2^-8.
#define MFMA_MX(a, b, c, sa, sb) \
  __builtin_amdgcn_mfma_scale_f32_16x16x128_f8f6f4((a), (b), (c), 0, 0, 0, (sa), 0, (sb))

__device__ __forceinline__ void dma16(const void* g, void* l){
  __builtin_amdgcn_global_load_lds(
      (const __attribute__((address_space(1))) uint32_t*)g,
      (__attribute__((address_space(3))) uint32_t*)l, 16, 0, 0);
}
// split-fp8 h: H = fp8(16h), L = fp8(16*(16h - dec(H)))
__device__ __forceinline__ void emit2(uint8_t* bH, uint8_t* bL, int off, float h){
  float h16 = h * 16.f;
  int p1 = __builtin_amdgcn_cvt_pk_fp8_f32(h16, h16, 0, false);
  float dec = __builtin_amdgcn_cvt_f32_fp8(p1, 0);
  float r16 = (h16 - dec) * 16.f;
  int p2 = __builtin_amdgcn_cvt_pk_fp8_f32(r16, r16, 0, false);
  bH[off] = (uint8_t)(p1 & 0xff);
  bL[off] = (uint8_t)(p2 & 0xff);
}

// ---------------------------------------------------------------------------
__global__ __launch_bounds__(256) void k_sniff(const uint32_t* __restrict__ e,
                                               int* __restrict__ flag)
{
  __shared__ int cnt;
  int tid = threadIdx.x;
  if (tid == 0) cnt = 0;
  __syncthreads();
  uint32_t u = e[tid];
  uint32_t ex = (u >> 7) & 0xFFu;
  if (ex >= 0x60u && ex <= 0x7Eu) atomicAdd(&cnt, 1);
  __syncthreads();
  if (tid == 0) flag[0] = (cnt >= 192) ? 1 : 0;
}

// ---------------------------------------------------------------------------
struct CvtDesc { const void* s; uint16_t* d; int n; int c0; };
struct CvtArgs { CvtDesc a[13]; };

__global__ __launch_bounds__(256) void k_cvt(CvtArgs A, const int* __restrict__ flag)
{
  int ch = blockIdx.x;
  int i = 0;
  #pragma unroll
  for (int k = 1; k < 13; ++k) if (ch >= A.a[k].c0) i = k;
  const void* s = A.a[i].s;
  uint16_t*   d = A.a[i].d;
  int n = A.a[i].n;
  int base = (ch - A.a[i].c0) * 4096 + threadIdx.x;
  int isb = *flag;
  #pragma unroll 4
  for (int r = 0; r < 16; ++r) {
    int idx = base + r * 256;
    if (idx < n)
      d[idx] = isb ? ((const uint16_t*)s)[idx] : f2bf(((const float*)s)[idx]);
  }
}

// ---------------------------------------------------------------------------
__global__ __launch_bounds__(256) void k_prep(
    const uint16_t* __restrict__ c1w, const uint16_t* __restrict__ c2w,
    const uint16_t* __restrict__ wih, const uint16_t* __restrict__ whh,
    uint16_t* __restrict__ fragC, uint16_t* __restrict__ fragI,
    uint2* __restrict__ fragH8, float* __restrict__ bnbuf,
    float* __restrict__ wsHf, float* __restrict__ wsC)
{
  int g = blockIdx.x * 256 + threadIdx.x;
  if (g < 20480) {                       // conv B fragments (320 tiles)
    int tile = g >> 6, lane = g & 63;
    int kt = tile >> 4, nt = tile & 15;
    int q = lane >> 4, c16 = lane & 15;
    int dlt = kt >> 2;
    int o = nt * 16 + c16;
    union { int4 i; uint16_t u[8]; } v;
    #pragma unroll
    for (int j = 0; j < 8; ++j) {
      int i = (kt & 3) * 32 + q * 8 + j;
      uint16_t val = 0;
      if (o < 128) { int k = dlt - 1; if (k >= 0 && k < 3) val = c1w[(o*128 + i)*3 + k]; }
      else         { int k = dlt;     if (k < 5)           val = c2w[((o-128)*128 + i)*5 + k]; }
      v.u[j] = val;
    }
    *(int4*)(fragC + tile * 512 + lane * 8) = v.i;
  } else if (g < 53248) {                // w_ih bf16 fragments (512 tiles)
    int gg = g - 20480;
    int tile = gg >> 6, lane = gg & 63;
    int nt = tile >> 3, kt = tile & 7;
    int q = lane >> 4, c16 = lane & 15;
    *(int4*)(fragI + tile * 512 + lane * 8) =
        *(const int4*)(wih + (nt*16 + c16)*256 + kt*32 + q*8);
  } else if (g < 86016) {                // w_hh fp8 MX fragments (x16 scale)
    int gg = g - 53248;
    int item = gg >> 2, part = gg & 3;
    int tile = item >> 6, lane = item & 63;    // tile = nt*2 + kb
    int nt = tile >> 1, kb = tile & 1;
    int q = lane >> 4, c16 = lane & 15;
    const uint16_t* src = whh + (nt*16 + c16)*256 + kb*128 + q*32 + part*8;
    float f[8];
    #pragma unroll
    for (int j = 0; j < 8; ++j) f[j] = bf2f(src[j]) * 16.f;
    int lo = __builtin_amdgcn_cvt_pk_fp8_f32(f[0], f[1], 0, false);
    lo     = __builtin_amdgcn_cvt_pk_fp8_f32(f[2], f[3], lo, true);
    int hi = __builtin_amdgcn_cvt_pk_fp8_f32(f[4], f[5], 0, false);
    hi     = __builtin_amdgcn_cvt_pk_fp8_f32(f[6], f[7], hi, true);
    fragH8[(tile*64 + lane)*4 + part] = make_uint2((uint32_t)lo, (uint32_t)hi);
  } else if (g < 102400) {               // zero wsHf (65536 f32)
    ((int4*)wsHf)[g - 86016] = make_int4(0,0,0,0);
  } else if (g < 118784) {               // zero wsC (65536 f32)
    ((int4*)wsC)[g - 102400] = make_int4(0,0,0,0);
  } else if (g < 118912) {               // zero bn sums (512 f32)
    ((int4*)bnbuf)[g - 118784] = make_int4(0,0,0,0);
  }
}

// ---------------------------------------------------------------------------
__global__ __launch_bounds__(256) void k_conv(
    const int* __restrict__ x, const uint16_t* __restrict__ etab,
    const uint16_t* __restrict__ fragC,
    const uint16_t* __restrict__ c1b, const uint16_t* __restrict__ c2b,
    uint16_t* __restrict__ y, float* __restrict__ bnbuf)
{
  __shared__ __align__(16) uint16_t embS[68 * 136];
  int blk = blockIdx.x;
  int b = blk >> 3, t0 = (blk & 7) * 64;
  int tid = threadIdx.x;
  int lane = tid & 63, w = tid >> 6;
  int q = lane >> 4, c16 = lane & 15;

  for (int s = tid; s < 1088; s += 256) {      // 68 rows x 16 segs of 16B
    int r = s >> 4, seg = s & 15;
    int t = t0 - 2 + r;
    int4 val = make_int4(0,0,0,0);
    if (t >= 0 && t < 512) {
      int idx = x[b*512 + t];
      val = *(const int4*)(etab + (size_t)idx*128 + seg*8);
    }
    *(int4*)(embS + r*136 + seg*8) = val;
  }
  __syncthreads();

  f32x4 acc[4][4];
  #pragma unroll
  for (int i = 0; i < 4; ++i)
    #pragma unroll
    for (int j = 0; j < 4; ++j) acc[i][j] = (f32x4){0.f,0.f,0.f,0.f};

  #pragma unroll 4
  for (int kt = 0; kt < 20; ++kt) {
    int dlt = kt >> 2;
    int i0 = (kt & 3)*32 + q*8;
    bf16x8 a[4];
    #pragma unroll
    for (int Mt = 0; Mt < 4; ++Mt)
      a[Mt] = ld_frag(embS + (Mt*16 + c16 + dlt)*136 + i0);
    #pragma unroll
    for (int ntl = 0; ntl < 4; ++ntl) {
      int nt = w*4 + ntl;
      bf16x8 bf = ld_frag(fragC + (kt*16 + nt)*512 + lane*8);
      #pragma unroll
      for (int Mt = 0; Mt < 4; ++Mt)
        acc[ntl][Mt] = mfma16(a[Mt], bf, acc[ntl][Mt]);
    }
  }

  #pragma unroll
  for (int ntl = 0; ntl < 4; ++ntl) {
    int ch = (w*4 + ntl)*16 + c16;
    float bias = bf2f(ch < 128 ? c1b[ch] : c2b[ch - 128]);
    float s0 = 0.f, s1 = 0.f;
    #pragma unroll
    for (int Mt = 0; Mt < 4; ++Mt) {
      #pragma unroll
      for (int r = 0; r < 4; ++r) {
        float v = acc[ntl][Mt][r] + bias;
        int t = t0 + Mt*16 + q*4 + r;
        y[((size_t)b*512 + t)*256 + ch] = f2bf(v);
        s0 += v; s1 += v*v;
      }
    }
    s0 += __shfl_xor(s0, 16); s0 += __shfl_xor(s0, 32);
    s1 += __shfl_xor(s1, 16); s1 += __shfl_xor(s1, 32);
    if (q == 0) { atomicAdd(&bnbuf[ch], s0); atomicAdd(&bnbuf[256 + ch], s1); }
  }
}

// ---------------------------------------------------------------------------
__global__ void k_bn(const uint16_t* __restrict__ gamma,
                     const uint16_t* __restrict__ beta,
                     float* __restrict__ bnbuf)
{
  int c = threadIdx.x;
  const float inv = 1.f / 131072.f;
  float mean = bnbuf[c] * inv;
  float var  = fmaxf(bnbuf[256 + c] * inv - mean*mean, 0.f);
  float sc   = bf2f(gamma[c]) * rsqrtf(var + 1e-5f);
  bnbuf[512 + c] = sc;
  bnbuf[768 + c] = bf2f(beta[c]) - mean * sc;
}

// ---------------------------------------------------------------------------
// k_gx: per-(t, b4-group) 8KB slab [nt 0..63][c16 0..15][r 0..3] bf16, TRUE
// scale (MX scales in k_lstm handle plane scaling). Slab = 4096 ushorts.
// ---------------------------------------------------------------------------
__global__ __launch_bounds__(256) void k_gx(
    const uint16_t* __restrict__ y, const float* __restrict__ bnbuf,
    const uint16_t* __restrict__ fragI, const uint16_t* __restrict__ bih,
    const uint16_t* __restrict__ bhh, uint16_t* __restrict__ gx, int tbase)
{
  __shared__ __align__(16) uint16_t aS[16384];
  int Mblk = blockIdx.x, Nblk = blockIdx.y;
  int tl = Mblk >> 2;
  int b0 = (Mblk & 3) * 64;
  int t = tbase + tl;
  int tid = threadIdx.x, lane = tid & 63, w = tid >> 6;
  int q = lane >> 4, c16 = lane & 15;

  for (int s = tid; s < 2048; s += 256) {
    int row = s >> 5, seg = s & 31;
    union { int4 i; uint16_t u[8]; } vv, oo;
    vv.i = *(const int4*)(y + ((size_t)(b0 + row)*512 + t)*256 + seg*8);
    #pragma unroll
    for (int j = 0; j < 8; ++j) {
      int ch = seg*8 + j;
      float f = bf2f(vv.u[j]) * bnbuf[512 + ch] + bnbuf[768 + ch];
      oo.u[j] = f2bf(fmaxf(f, 0.f));
    }
    int Mt = row >> 4, mL = row & 15, kt2 = seg >> 2, qq = seg & 3;
    *(int4*)(aS + ((Mt*8 + kt2)*64 + qq*16 + mL)*8) = oo.i;
  }
  __syncthreads();

  f32x4 acc[4][4];
  #pragma unroll
  for (int ntl = 0; ntl < 4; ++ntl) {
    int n = (Nblk*16 + w*4 + ntl)*16 + c16;
    float bias = bf2f(bih[n]) + bf2f(bhh[n]);
    #pragma unroll
    for (int Mt = 0; Mt < 4; ++Mt) acc[ntl][Mt] = (f32x4){bias,bias,bias,bias};
  }
  #pragma unroll
  for (int kt = 0; kt < 8; ++kt) {
    bf16x8 a[4];
    #pragma unroll
    for (int Mt = 0; Mt < 4; ++Mt)
      a[Mt] = ld_frag(aS + ((Mt*8 + kt)*64 + lane)*8);
    #pragma unroll
    for (int ntl = 0; ntl < 4; ++ntl) {
      int nt = Nblk*16 + w*4 + ntl;
      bf16x8 bf = ld_frag(fragI + ((size_t)(nt*8 + kt))*512 + lane*8);
      #pragma unroll
      for (int Mt = 0; Mt < 4; ++Mt)
        acc[ntl][Mt] = mfma16(a[Mt], bf, acc[ntl][Mt]);
    }
  }
  #pragma unroll
  for (int ntl = 0; ntl < 4; ++ntl) {
    int nt = Nblk*16 + w*4 + ntl;
    #pragma unroll
    for (int Mt = 0; Mt < 4; ++Mt) {
      // D rows m=q*4+r -> b4 = (Mblk&3)*16 + Mt*4 + q, in-block row r
      int b4 = (Mblk & 3)*16 + Mt*4 + q;
      uint32_t lo = (uint32_t)f2bf(acc[ntl][Mt][0]) | ((uint32_t)f2bf(acc[ntl][Mt][1]) << 16);
      uint32_t hi = (uint32_t)f2bf(acc[ntl][Mt][2]) | ((uint32_t)f2bf(acc[ntl][Mt][3]) << 16);
      uint2 vv = {lo, hi};
      *(uint2*)(gx + ((size_t)(tl*64 + b4))*4096 + (nt*16 + c16)*4) = vv;
    }
  }
}

// ---------------------------------------------------------------------------
// k_lstm v12: 256 blocks x 512 threads (8 waves, 2/SIMD), ONE batch row per
// block. Wave w owns 8 gate tiles ntg[gp]=(gp>>1)*16+2w+(gp&1) covering
// units u=32w..32w+31 x 4 gates. breg = w_hh fp8 MX frags (resident).
// h split-fp8 H/L planes, 32B slot stride: h[u] at byte (u>>5)*512+(u&31)
// (slot (u>>5)*16 + m, m=0; rows 1..15 zeroed once). gx staged via dma16
// dbuf slabs; q==0 lanes read gate biases from gxS and run gates directly
// from acc[gp][0]. ODD waves raise prio around the MFMA cluster so the two
// waves on each SIMD de-lockstep: odd's gate VALU runs under even's MFMAs.
// One __syncthreads per step. Block exits at own lengths[row].
// ---------------------------------------------------------------------------
__global__ __launch_bounds__(512, 2) void k_lstm(
    const uint16_t* __restrict__ gx, const uint2* __restrict__ fragH8,
    const int* __restrict__ lengths, float* __restrict__ wsHf,
    float* __restrict__ wsC, float* __restrict__ hn,
    int tbase, int tcount, int last)
{
  // [buf][plane H/L][128 slots x 32B]
  __shared__ __align__(16) uint8_t hP[2][2][4096];
  __shared__ __align__(16) uint8_t gxS[2][8192];

  int row = blockIdx.x;
  int tid = threadIdx.x, lane = tid & 63, w = tid >> 6;   // w = 0..7
  int q = lane >> 4, c16 = lane & 15;

  int li   = lengths[row];
  int b4g  = row >> 2, rloc = row & 3;

  int ntg[8];
  i32x8 breg[8][2];                            // w_hh fp8 MX, fully resident
  #pragma unroll
  for (int gp = 0; gp < 8; ++gp) {
    ntg[gp] = (gp >> 1)*16 + 2*w + (gp & 1);
    #pragma unroll
    for (int kb = 0; kb < 2; ++kb) {
      const int4* s4 = (const int4*)&fragH8[((ntg[gp]*2 + kb)*64 + lane)*4];
      union { int4 i[2]; i32x8 v; } u;
      u.i[0] = s4[0]; u.i[1] = s4[1];
      breg[gp][kb] = u.v;
    }
  }

  // q==0 lanes own 2 cells: u = 32w + p*16 + c16 (slot (u>>5)*16, byte u&31)
  int up[2], off2[2];
  #pragma unroll
  for (int p = 0; p < 2; ++p) {
    int u = 32*w + p*16 + c16;
    up[p] = u;
    off2[p] = (u >> 5)*512 + (u & 31);
  }

  float cr[2] = {0.f, 0.f}, hr[2] = {0.f, 0.f};
  if (q == 0) {
    #pragma unroll
    for (int p = 0; p < 2; ++p) {
      cr[p] = wsC [row*256 + up[p]];
      hr[p] = wsHf[row*256 + up[p]];
    }
  }

  // zero plane buffers (covers pad rows 1..15 forever): 16384B / 512 thr
  ((int4*)hP)[tid]       = make_int4(0,0,0,0);
  ((int4*)hP)[tid + 512] = make_int4(0,0,0,0);
  __syncthreads();
  if (q == 0) {
    #pragma unroll
    for (int p = 0; p < 2; ++p)
      emit2(&hP[0][0][0], &hP[0][1][0], off2[p], hr[p]);
  }
  // initial gx slab (slab index tl=0 -> b4g)
  dma16((const uint8_t*)(gx + (size_t)b4g*4096) + tid*16, &gxS[0][tid*16]);
  __syncthreads();

  int wodd = w & 1;
  int cur = 0;
  int tEnd = min(tbase + tcount, li);

  for (int t = tbase; t < tEnd; ++t) {
    // stage next step's gx slab
    {
      int tn = (t + 1 < tEnd) ? (t + 1 - tbase) : (t - tbase);
      dma16((const uint8_t*)(gx + ((size_t)(tn*64 + b4g))*4096) + tid*16,
            &gxS[cur ^ 1][tid*16]);
    }

    f32x4 acc[8];
    #pragma unroll
    for (int gp = 0; gp < 8; ++gp) acc[gp] = (f32x4){0.f,0.f,0.f,0.f};

    // GEMM: H and L planes via MX MFMA, weights in registers.
    // Asymmetric priority: odd waves drain their cluster first, then run
    // gate VALU under the even wave's MFMAs (de-lockstep the SIMD pair).
    // scales: H-plane 2^-4 * 2^-4 (h x16, w x16); L-plane 2^-8 * 2^-4.
    if (wodd) __builtin_amdgcn_s_setprio(1);
    #pragma unroll
    for (int kb = 0; kb < 2; ++kb) {
      int ao = ((kb*4 + q)*16 + c16)*32;
      union { int4 i[2]; i32x8 v; } aH, aL;
      aH.i[0] = *(const int4*)&hP[cur][0][ao];
      aH.i[1] = *(const int4*)&hP[cur][0][ao + 16];
      aL.i[0] = *(const int4*)&hP[cur][1][ao];
      aL.i[1] = *(const int4*)&hP[cur][1][ao + 16];
      #pragma unroll
      for (int gp = 0; gp < 8; ++gp) {
        acc[gp] = MFMA_MX(aH.v, breg[gp][kb], acc[gp], 0x7B7B7B7B, 0x7B7B7B7B);
        acc[gp] = MFMA_MX(aL.v, breg[gp][kb], acc[gp], 0x77777777, 0x7B7B7B7B);
      }
    }
    if (wodd) __builtin_amdgcn_s_setprio(0);

    // gates + emit: row m=0 lives in q==0 lanes, elem 0; gate gd of unit
    // u=32w+p*16+c16 is acc[gd*2+p][0]. gx bias from staged slab.
    if (q == 0) {
      const uint16_t* gs = (const uint16_t*)&gxS[cur][0];
      float pre[8];
      #pragma unroll
      for (int gp = 0; gp < 8; ++gp)
        pre[gp] = acc[gp][0] + bf2f(gs[(ntg[gp]*16 + c16)*4 + rloc]);
      #pragma unroll
      for (int p = 0; p < 2; ++p) {
        float cn = sigm(pre[2 + p])*cr[p] + sigm(pre[0 + p])*tanh_(pre[4 + p]);
        float hw = sigm(pre[6 + p])*tanh_(cn);
        cr[p] = cn; hr[p] = hw;
        emit2(&hP[cur ^ 1][0][0], &hP[cur ^ 1][1][0], off2[p], hw);
      }
    }
    __syncthreads();
    cur ^= 1;
  }

  if (q == 0) {
    #pragma unroll
    for (int p = 0; p < 2; ++p) {
      wsC [row*256 + up[p]] = cr[p];
      wsHf[row*256 + up[p]] = hr[p];
    }
    if (last) {
      #pragma unroll
      for (int p = 0; p < 2; ++p)
        hn[row*256 + up[p]] = hr[p];
    }
  }
}

// ---------------------------------------------------------------------------
__global__ __launch_bounds__(256) void k_attn(
    const uint16_t* __restrict__ y, const float* __restrict__ hn,
    const uint16_t* __restrict__ linw, const uint16_t* __restrict__ linb,
    void* __restrict__ outv, const int* __restrict__ flag)
{
  __shared__ float hnS[256];
  __shared__ float attnS[512];
  int b = blockIdx.x;
  int tid = threadIdx.x, lane = tid & 63, w = tid >> 6;
  int isb = *flag;
  hnS[tid] = hn[b*256 + tid];
  __syncthreads();
  for (int t = w; t < 512; t += 4) {
    uint2 d = *(const uint2*)(y + ((size_t)b*512 + t)*256 + lane*4);
    float s = bf2f((uint16_t)(d.x & 0xffffu)) * hnS[lane*4 + 0]
            + bf2f((uint16_t)(d.x >> 16))     * hnS[lane*4 + 1]
            + bf2f((uint16_t)(d.y & 0xffffu)) * hnS[lane*4 + 2]
            + bf2f((uint16_t)(d.y >> 16))     * hnS[lane*4 + 3];
    #pragma unroll
    for (int off = 32; off >= 1; off >>= 1) s += __shfl_xor(s, off);
    if (lane == 0) attnS[t] = s * 0.0625f;     // 1/sqrt(256)
  }
  __syncthreads();
  float acc = 0.f;
  #pragma unroll 4
  for (int t = 0; t < 512; ++t)
    acc += attnS[t] * bf2f(y[((size_t)b*512 + t)*256 + tid]);
  if (isb) ((uint16_t*)outv)[7936 + b*256 + tid] = f2bf(acc);
  else     ((float*)outv)[7936 + b*256 + tid] = acc;
  if (tid < 31) {
    float a2 = bf2f(linb[tid]);
    for (int k = 0; k < 256; ++k) a2 += hnS[k] * bf2f(linw[tid*256 + k]);
    if (isb) ((uint16_t*)outv)[b*31 + tid] = f2bf(a2);
    else     ((float*)outv)[b*31 + tid] = a2;
  }
}

// ---------------------------------------------------------------------------
extern "C" void kernel_launch(void* const* d_in, const int* in_sizes, int n_in,
                              void* d_out, int out_size, void* d_ws, size_t ws_size,
                              hipStream_t stream)
{
  (void)in_sizes; (void)out_size;
  if (n_in < 15) return;
  const int* x   = (const int*)d_in[0];
  const int* len = (const int*)d_in[1];

  uint8_t* p = (uint8_t*)d_ws;
  auto take = [&](size_t n){ uint8_t* r = p; p += (n + 255) & ~(size_t)255; return r; };
  int*      flag  = (int*)take(256);
  uint16_t* c1bC  = (uint16_t*)take(256);
  uint16_t* c2bC  = (uint16_t*)take(256);
  uint16_t* bngC  = (uint16_t*)take(512);
  uint16_t* bnbC  = (uint16_t*)take(512);
  uint16_t* bihC  = (uint16_t*)take(2048);
  uint16_t* bhhC  = (uint16_t*)take(2048);
  uint16_t* linwC = (uint16_t*)take(15872);
  uint16_t* linbC = (uint16_t*)take(64);
  uint16_t* fragC = (uint16_t*)take(327680);
  uint16_t* fragI = (uint16_t*)take(524288);
  uint2*    fragH8= (uint2*)take(262144);
  float*    bnbuf = (float*)take(4096);
  float*    wsHf  = (float*)take(262144);
  float*    wsC   = (float*)take(262144);
  float*    hnbuf = (float*)take(262144);
  uint16_t* y     = (uint16_t*)take(67108864ull);

  // gxb: 256MB (single-chunk, all 512 t) if workspace allows, else 64MB
  // (4-chunk). Host-side branch only; kernels are identical.
  size_t prefix = (size_t)(p - (uint8_t*)d_ws);
  bool big = (prefix + 268435456ull) <= ws_size;
  uint16_t* gxb = (uint16_t*)take(big ? 268435456ull : 67108864ull);
  if ((size_t)(p - (uint8_t*)d_ws) > ws_size) return;

  // big converted tensors live inside gxb (dead before k_gx first writes it)
  uint16_t* etabC = gxb;
  uint16_t* c1wC  = (uint16_t*)((uint8_t*)gxb + 16u*1024*1024);
  uint16_t* c2wC  = (uint16_t*)((uint8_t*)gxb + 17u*1024*1024);
  uint16_t* wihC  = (uint16_t*)((uint8_t*)gxb + 18u*1024*1024);
  uint16_t* whhC  = (uint16_t*)((uint8_t*)gxb + 19u*1024*1024);

  k_sniff<<<1, 256, 0, stream>>>((const uint32_t*)d_in[2], flag);

  CvtArgs A;
  int c0 = 0;
  auto put = [&](int i, const void* s, uint16_t* d, int n){
    A.a[i].s = s; A.a[i].d = d; A.a[i].n = n; A.a[i].c0 = c0;
    c0 += (n + 4095) / 4096;
  };
  put(0,  d_in[2],  etabC, 6400000);
  put(1,  d_in[3],  c1wC,  49152);
  put(2,  d_in[4],  c1bC,  128);
  put(3,  d_in[5],  c2wC,  81920);
  put(4,  d_in[6],  c2bC,  128);
  put(5,  d_in[7],  bngC,  256);
  put(6,  d_in[8],  bnbC,  256);
  put(7,  d_in[9],  wihC,  262144);
  put(8,  d_in[10], whhC,  262144);
  put(9,  d_in[11], bihC,  1024);
  put(10, d_in[12], bhhC,  1024);
  put(11, d_in[13], linwC, 7936);
  put(12, d_in[14], linbC, 31);
  k_cvt<<<c0, 256, 0, stream>>>(A, flag);

  k_prep<<<512, 256, 0, stream>>>(c1wC, c2wC, wihC, whhC, fragC, fragI, fragH8,
                                  bnbuf, wsHf, wsC);
  k_conv<<<2048, 256, 0, stream>>>(x, etabC, fragC, c1bC, c2bC, y, bnbuf);
  k_bn<<<1, 256, 0, stream>>>(bngC, bnbC, bnbuf);
  if (big) {
    // one gx pass over all 512 timesteps, one 512-step lstm launch
    k_gx<<<dim3(2048, 4), 256, 0, stream>>>(y, bnbuf, fragI, bihC, bhhC, gxb, 0);
    k_lstm<<<256, 512, 0, stream>>>(gxb, fragH8, len, wsHf, wsC, hnbuf,
                                    0, 512, 1);
  } else {
    for (int c = 0; c < 4; ++c) {
      k_gx<<<dim3(512, 4), 256, 0, stream>>>(y, bnbuf, fragI, bihC, bhhC, gxb, c*128);
      k_lstm<<<256, 512, 0, stream>>>(gxb, fragH8, len, wsHf, wsC, hnbuf,
                                      c*128, 128, (c == 3) ? 1 : 0);
    }
  }
  k_attn<<<256, 256, 0, stream>>>(y, hnbuf, linwC, linbC, d_out, flag);
}

// Round 10
// 1237.764 us; speedup vs baseline: 1.0079x; 1.0079x over previous
//
#include <hip/hip_runtime.h>
#include <stdint.h>

// ---------------------------------------------------------------------------
// RNNClassifier pipeline for MI355X (gfx950). Dtype-agnostic input handling
// (sniffer + converter to bf16). Core pipeline (MFMA, f32 accum):
//  k_prep : conv/w_ih weights -> bf16 MFMA B-frags; w_hh -> fp8 e4m3 MX
//           B-frags (16x16x128 layout) scaled x16; zero carries.
//  k_conv : embedding gather + (conv3|conv5) as one K=640 im2col GEMM -> y
//  k_bn   : finalize BN scale/shift
//  k_gx   : gx = ReLU(BN(y)) @ w_ih^T + b_ih + b_hh, TRUE scale, written as
//           8KB slabs per (t, 4-row group) [nt][c16][r] bf16
//  k_lstm : v8c FINAL (best measured: 206-207us/128-step launch, twice
//           reproduced). 256 blocks x 1 row x 512 thr (8 waves, 2/SIMD).
//           All 4 gates of a unit land in the SAME q==0 lane's acc
//           (gp=gate*2+p, elem 0) -> gate math direct from accumulators.
//           gx staged via dma16 dbuf LDS slabs; h split-fp8 H/L planes at
//           32B slot stride. Per-block exit at own lengths[row].
//           CEILING NOTE: step = 3880 cyc/SIMD = 2214 MX-MFMA pipe floor
//           (MfmaUtil 54% ~= floor/step) + ~1550 VALU + ~200 barrier. The
//           chain MFMA(t)->gates(t)->emit(t)->barrier->MFMA(t+1) is serial
//           by data dependency; 5 independent overlap attempts (v9 C-init
//           fold, v10 swizzle+fused-emit, v11 sym setprio, issue-early
//           reads, v12 asym setprio) all measured null-to-negative
//           (207->239/212/228/210). Single-plane fp8 would halve the MFMA
//           floor but the h-quantization error accumulated over 512 steps
//           risks the 0.038 absmax budget (currently 0.0195). This is the
//           structure's HIP-source plateau.
//  k_attn : attn/attn_out/logits epilogue
//  Launcher: if ws_size allows a 256MB gxb, run ONE k_gx (512 t) + ONE
//           k_lstm (512 steps); byte-identical 4-chunk fallback otherwise.
//
// MFMA 16x16x32 layouts (bf16 verified m89/m120):
//   A: lane holds A[m=lane&15][k=(lane>>4)*8+j], j=0..7
//   B: lane holds B[k=(lane>>4)*8+j][n=lane&15]
//   C/D: lane holds D[m=(lane>>4)*4+r][n=lane&15], r=0..3
// MX 16x16x128 f8f6f4 (natural 4x K extension, A/B symmetric k-map):
//   A: lane holds A[m=lane&15][k=(lane>>4)*32+j], j=0..31; B mirrored.
//   One e8m0 scale byte per 32-block; bytes replicated in the i32 scale
//   operand -> opsel-immune.
// ---------------------------------------------------------------------------

typedef __bf16 bf16x8 __attribute__((ext_vector_type(8)));
typedef float  f32x4  __attribute__((ext_vector_type(4)));
typedef int    i32x8  __attribute__((ext_vector_type(8)));

__device__ __forceinline__ float bf2f(uint16_t h){
  union { uint32_t u; float f; } v; v.u = ((uint32_t)h) << 16; return v.f;
}
__device__ __forceinline__ uint16_t f2bf(float f){
  union { float f; uint32_t u; } v; v.f = f;
  return (uint16_t)((v.u + 0x7FFFu + ((v.u >> 16) & 1u)) >> 16);
}
__device__ __forceinline__ bf16x8 ld_frag(const uint16_t* p){
  union { int4 i; bf16x8 b; } u; u.i = *(const int4*)p; return u.b;
}
__device__ __forceinline__ f32x4 mfma16(bf16x8 a, bf16x8 b, f32x4 c){
  return __builtin_amdgcn_mfma_f32_16x16x32_bf16(a, b, c, 0, 0, 0);
}
__device__ __forceinline__ float sigm(float x){
  return __builtin_amdgcn_rcpf(1.f + __expf(-x));
}
__device__ __forceinline__ float tanh_(float x){
  return 2.f * __builtin_amdgcn_rcpf(1.f + __expf(-2.f * x)) - 1.f;
}

// MX MFMA: imm args must be literal at the builtin callsite -> macro.
// scales: e8m0 bytes replicated; 0x7B = 2^-4, 0x77 = 2^-8.
#define MFMA_MX(a, b, c, sa, sb) \
  __builtin_amdgcn_mfma_scale_f32_16x16x128_f8f6f4((a), (b), (c), 0, 0, 0, (sa), 0, (sb))

__device__ __forceinline__ void dma16(const void* g, void* l){
  __builtin_amdgcn_global_load_lds(
      (const __attribute__((address_space(1))) uint32_t*)g,
      (__attribute__((address_space(3))) uint32_t*)l, 16, 0, 0);
}
// split-fp8 h: H = fp8(16h), L = fp8(16*(16h - dec(H)))
__device__ __forceinline__ void emit2(uint8_t* bH, uint8_t* bL, int off, float h){
  float h16 = h * 16.f;
  int p1 = __builtin_amdgcn_cvt_pk_fp8_f32(h16, h16, 0, false);
  float dec = __builtin_amdgcn_cvt_f32_fp8(p1, 0);
  float r16 = (h16 - dec) * 16.f;
  int p2 = __builtin_amdgcn_cvt_pk_fp8_f32(r16, r16, 0, false);
  bH[off] = (uint8_t)(p1 & 0xff);
  bL[off] = (uint8_t)(p2 & 0xff);
}

// ---------------------------------------------------------------------------
__global__ __launch_bounds__(256) void k_sniff(const uint32_t* __restrict__ e,
                                               int* __restrict__ flag)
{
  __shared__ int cnt;
  int tid = threadIdx.x;
  if (tid == 0) cnt = 0;
  __syncthreads();
  uint32_t u = e[tid];
  uint32_t ex = (u >> 7) & 0xFFu;
  if (ex >= 0x60u && ex <= 0x7Eu) atomicAdd(&cnt, 1);
  __syncthreads();
  if (tid == 0) flag[0] = (cnt >= 192) ? 1 : 0;
}

// ---------------------------------------------------------------------------
struct CvtDesc { const void* s; uint16_t* d; int n; int c0; };
struct CvtArgs { CvtDesc a[13]; };

__global__ __launch_bounds__(256) void k_cvt(CvtArgs A, const int* __restrict__ flag)
{
  int ch = blockIdx.x;
  int i = 0;
  #pragma unroll
  for (int k = 1; k < 13; ++k) if (ch >= A.a[k].c0) i = k;
  const void* s = A.a[i].s;
  uint16_t*   d = A.a[i].d;
  int n = A.a[i].n;
  int base = (ch - A.a[i].c0) * 4096 + threadIdx.x;
  int isb = *flag;
  #pragma unroll 4
  for (int r = 0; r < 16; ++r) {
    int idx = base + r * 256;
    if (idx < n)
      d[idx] = isb ? ((const uint16_t*)s)[idx] : f2bf(((const float*)s)[idx]);
  }
}

// ---------------------------------------------------------------------------
__global__ __launch_bounds__(256) void k_prep(
    const uint16_t* __restrict__ c1w, const uint16_t* __restrict__ c2w,
    const uint16_t* __restrict__ wih, const uint16_t* __restrict__ whh,
    uint16_t* __restrict__ fragC, uint16_t* __restrict__ fragI,
    uint2* __restrict__ fragH8, float* __restrict__ bnbuf,
    float* __restrict__ wsHf, float* __restrict__ wsC)
{
  int g = blockIdx.x * 256 + threadIdx.x;
  if (g < 20480) {                       // conv B fragments (320 tiles)
    int tile = g >> 6, lane = g & 63;
    int kt = tile >> 4, nt = tile & 15;
    int q = lane >> 4, c16 = lane & 15;
    int dlt = kt >> 2;
    int o = nt * 16 + c16;
    union { int4 i; uint16_t u[8]; } v;
    #pragma unroll
    for (int j = 0; j < 8; ++j) {
      int i = (kt & 3) * 32 + q * 8 + j;
      uint16_t val = 0;
      if (o < 128) { int k = dlt - 1; if (k >= 0 && k < 3) val = c1w[(o*128 + i)*3 + k]; }
      else         { int k = dlt;     if (k < 5)           val = c2w[((o-128)*128 + i)*5 + k]; }
      v.u[j] = val;
    }
    *(int4*)(fragC + tile * 512 + lane * 8) = v.i;
  } else if (g < 53248) {                // w_ih bf16 fragments (512 tiles)
    int gg = g - 20480;
    int tile = gg >> 6, lane = gg & 63;
    int nt = tile >> 3, kt = tile & 7;
    int q = lane >> 4, c16 = lane & 15;
    *(int4*)(fragI + tile * 512 + lane * 8) =
        *(const int4*)(wih + (nt*16 + c16)*256 + kt*32 + q*8);
  } else if (g < 86016) {                // w_hh fp8 MX fragments (x16 scale)
    int gg = g - 53248;
    int item = gg >> 2, part = gg & 3;
    int tile = item >> 6, lane = item & 63;    // tile = nt*2 + kb
    int nt = tile >> 1, kb = tile & 1;
    int q = lane >> 4, c16 = lane & 15;
    const uint16_t* src = whh + (nt*16 + c16)*256 + kb*128 + q*32 + part*8;
    float f[8];
    #pragma unroll
    for (int j = 0; j < 8; ++j) f[j] = bf2f(src[j]) * 16.f;
    int lo = __builtin_amdgcn_cvt_pk_fp8_f32(f[0], f[1], 0, false);
    lo     = __builtin_amdgcn_cvt_pk_fp8_f32(f[2], f[3], lo, true);
    int hi = __builtin_amdgcn_cvt_pk_fp8_f32(f[4], f[5], 0, false);
    hi     = __builtin_amdgcn_cvt_pk_fp8_f32(f[6], f[7], hi, true);
    fragH8[(tile*64 + lane)*4 + part] = make_uint2((uint32_t)lo, (uint32_t)hi);
  } else if (g < 102400) {               // zero wsHf (65536 f32)
    ((int4*)wsHf)[g - 86016] = make_int4(0,0,0,0);
  } else if (g < 118784) {               // zero wsC (65536 f32)
    ((int4*)wsC)[g - 102400] = make_int4(0,0,0,0);
  } else if (g < 118912) {               // zero bn sums (512 f32)
    ((int4*)bnbuf)[g - 118784] = make_int4(0,0,0,0);
  }
}

// ---------------------------------------------------------------------------
__global__ __launch_bounds__(256) void k_conv(
    const int* __restrict__ x, const uint16_t* __restrict__ etab,
    const uint16_t* __restrict__ fragC,
    const uint16_t* __restrict__ c1b, const uint16_t* __restrict__ c2b,
    uint16_t* __restrict__ y, float* __restrict__ bnbuf)
{
  __shared__ __align__(16) uint16_t embS[68 * 136];
  int blk = blockIdx.x;
  int b = blk >> 3, t0 = (blk & 7) * 64;
  int tid = threadIdx.x;
  int lane = tid & 63, w = tid >> 6;
  int q = lane >> 4, c16 = lane & 15;

  for (int s = tid; s < 1088; s += 256) {      // 68 rows x 16 segs of 16B
    int r = s >> 4, seg = s & 15;
    int t = t0 - 2 + r;
    int4 val = make_int4(0,0,0,0);
    if (t >= 0 && t < 512) {
      int idx = x[b*512 + t];
      val = *(const int4*)(etab + (size_t)idx*128 + seg*8);
    }
    *(int4*)(embS + r*136 + seg*8) = val;
  }
  __syncthreads();

  f32x4 acc[4][4];
  #pragma unroll
  for (int i = 0; i < 4; ++i)
    #pragma unroll
    for (int j = 0; j < 4; ++j) acc[i][j] = (f32x4){0.f,0.f,0.f,0.f};

  #pragma unroll 4
  for (int kt = 0; kt < 20; ++kt) {
    int dlt = kt >> 2;
    int i0 = (kt & 3)*32 + q*8;
    bf16x8 a[4];
    #pragma unroll
    for (int Mt = 0; Mt < 4; ++Mt)
      a[Mt] = ld_frag(embS + (Mt*16 + c16 + dlt)*136 + i0);
    #pragma unroll
    for (int ntl = 0; ntl < 4; ++ntl) {
      int nt = w*4 + ntl;
      bf16x8 bf = ld_frag(fragC + (kt*16 + nt)*512 + lane*8);
      #pragma unroll
      for (int Mt = 0; Mt < 4; ++Mt)
        acc[ntl][Mt] = mfma16(a[Mt], bf, acc[ntl][Mt]);
    }
  }

  #pragma unroll
  for (int ntl = 0; ntl < 4; ++ntl) {
    int ch = (w*4 + ntl)*16 + c16;
    float bias = bf2f(ch < 128 ? c1b[ch] : c2b[ch - 128]);
    float s0 = 0.f, s1 = 0.f;
    #pragma unroll
    for (int Mt = 0; Mt < 4; ++Mt) {
      #pragma unroll
      for (int r = 0; r < 4; ++r) {
        float v = acc[ntl][Mt][r] + bias;
        int t = t0 + Mt*16 + q*4 + r;
        y[((size_t)b*512 + t)*256 + ch] = f2bf(v);
        s0 += v; s1 += v*v;
      }
    }
    s0 += __shfl_xor(s0, 16); s0 += __shfl_xor(s0, 32);
    s1 += __shfl_xor(s1, 16); s1 += __shfl_xor(s1, 32);
    if (q == 0) { atomicAdd(&bnbuf[ch], s0); atomicAdd(&bnbuf[256 + ch], s1); }
  }
}

// ---------------------------------------------------------------------------
__global__ void k_bn(const uint16_t* __restrict__ gamma,
                     const uint16_t* __restrict__ beta,
                     float* __restrict__ bnbuf)
{
  int c = threadIdx.x;
  const float inv = 1.f / 131072.f;
  float mean = bnbuf[c] * inv;
  float var  = fmaxf(bnbuf[256 + c] * inv - mean*mean, 0.f);
  float sc   = bf2f(gamma[c]) * rsqrtf(var + 1e-5f);
  bnbuf[512 + c] = sc;
  bnbuf[768 + c] = bf2f(beta[c]) - mean * sc;
}

// ---------------------------------------------------------------------------
// k_gx: per-(t, b4-group) 8KB slab [nt 0..63][c16 0..15][r 0..3] bf16, TRUE
// scale (MX scales in k_lstm handle plane scaling). Slab = 4096 ushorts.
// ---------------------------------------------------------------------------
__global__ __launch_bounds__(256) void k_gx(
    const uint16_t* __restrict__ y, const float* __restrict__ bnbuf,
    const uint16_t* __restrict__ fragI, const uint16_t* __restrict__ bih,
    const uint16_t* __restrict__ bhh, uint16_t* __restrict__ gx, int tbase)
{
  __shared__ __align__(16) uint16_t aS[16384];
  int Mblk = blockIdx.x, Nblk = blockIdx.y;
  int tl = Mblk >> 2;
  int b0 = (Mblk & 3) * 64;
  int t = tbase + tl;
  int tid = threadIdx.x, lane = tid & 63, w = tid >> 6;
  int q = lane >> 4, c16 = lane & 15;

  for (int s = tid; s < 2048; s += 256) {
    int row = s >> 5, seg = s & 31;
    union { int4 i; uint16_t u[8]; } vv, oo;
    vv.i = *(const int4*)(y + ((size_t)(b0 + row)*512 + t)*256 + seg*8);
    #pragma unroll
    for (int j = 0; j < 8; ++j) {
      int ch = seg*8 + j;
      float f = bf2f(vv.u[j]) * bnbuf[512 + ch] + bnbuf[768 + ch];
      oo.u[j] = f2bf(fmaxf(f, 0.f));
    }
    int Mt = row >> 4, mL = row & 15, kt2 = seg >> 2, qq = seg & 3;
    *(int4*)(aS + ((Mt*8 + kt2)*64 + qq*16 + mL)*8) = oo.i;
  }
  __syncthreads();

  f32x4 acc[4][4];
  #pragma unroll
  for (int ntl = 0; ntl < 4; ++ntl) {
    int n = (Nblk*16 + w*4 + ntl)*16 + c16;
    float bias = bf2f(bih[n]) + bf2f(bhh[n]);
    #pragma unroll
    for (int Mt = 0; Mt < 4; ++Mt) acc[ntl][Mt] = (f32x4){bias,bias,bias,bias};
  }
  #pragma unroll
  for (int kt = 0; kt < 8; ++kt) {
    bf16x8 a[4];
    #pragma unroll
    for (int Mt = 0; Mt < 4; ++Mt)
      a[Mt] = ld_frag(aS + ((Mt*8 + kt)*64 + lane)*8);
    #pragma unroll
    for (int ntl = 0; ntl < 4; ++ntl) {
      int nt = Nblk*16 + w*4 + ntl;
      bf16x8 bf = ld_frag(fragI + ((size_t)(nt*8 + kt))*512 + lane*8);
      #pragma unroll
      for (int Mt = 0; Mt < 4; ++Mt)
        acc[ntl][Mt] = mfma16(a[Mt], bf, acc[ntl][Mt]);
    }
  }
  #pragma unroll
  for (int ntl = 0; ntl < 4; ++ntl) {
    int nt = Nblk*16 + w*4 + ntl;
    #pragma unroll
    for (int Mt = 0; Mt < 4; ++Mt) {
      // D rows m=q*4+r -> b4 = (Mblk&3)*16 + Mt*4 + q, in-block row r
      int b4 = (Mblk & 3)*16 + Mt*4 + q;
      uint32_t lo = (uint32_t)f2bf(acc[ntl][Mt][0]) | ((uint32_t)f2bf(acc[ntl][Mt][1]) << 16);
      uint32_t hi = (uint32_t)f2bf(acc[ntl][Mt][2]) | ((uint32_t)f2bf(acc[ntl][Mt][3]) << 16);
      uint2 vv = {lo, hi};
      *(uint2*)(gx + ((size_t)(tl*64 + b4))*4096 + (nt*16 + c16)*4) = vv;
    }
  }
}

// ---------------------------------------------------------------------------
// k_lstm v8c: 256 blocks x 512 threads (8 waves, 2/SIMD), ONE batch row per
// block. Wave w owns 8 gate tiles ntg[gp]=(gp>>1)*16+2w+(gp&1) covering
// units u=32w..32w+31 x 4 gates. breg = w_hh fp8 MX frags (resident).
// h split-fp8 H/L planes, 32B slot stride: h[u] at byte (u>>5)*512+(u&31)
// (slot (u>>5)*16 + m, m=0; rows 1..15 zeroed once). gx staged via dma16
// dbuf slabs (8KB = 512x16B); q==0 lanes read gate biases from gxS and run
// gates directly from acc[gp][0]. One __syncthreads per step. Block exits
// at own lengths[row].
// ---------------------------------------------------------------------------
__global__ __launch_bounds__(512, 2) void k_lstm(
    const uint16_t* __restrict__ gx, const uint2* __restrict__ fragH8,
    const int* __restrict__ lengths, float* __restrict__ wsHf,
    float* __restrict__ wsC, float* __restrict__ hn,
    int tbase, int tcount, int last)
{
  // [buf][plane H/L][128 slots x 32B]
  __shared__ __align__(16) uint8_t hP[2][2][4096];
  __shared__ __align__(16) uint8_t gxS[2][8192];

  int row = blockIdx.x;
  int tid = threadIdx.x, lane = tid & 63, w = tid >> 6;   // w = 0..7
  int q = lane >> 4, c16 = lane & 15;

  int li   = lengths[row];
  int b4g  = row >> 2, rloc = row & 3;

  int ntg[8];
  i32x8 breg[8][2];                            // w_hh fp8 MX, fully resident
  #pragma unroll
  for (int gp = 0; gp < 8; ++gp) {
    ntg[gp] = (gp >> 1)*16 + 2*w + (gp & 1);
    #pragma unroll
    for (int kb = 0; kb < 2; ++kb) {
      const int4* s4 = (const int4*)&fragH8[((ntg[gp]*2 + kb)*64 + lane)*4];
      union { int4 i[2]; i32x8 v; } u;
      u.i[0] = s4[0]; u.i[1] = s4[1];
      breg[gp][kb] = u.v;
    }
  }

  // q==0 lanes own 2 cells: u = 32w + p*16 + c16 (slot (u>>5)*16, byte u&31)
  int up[2], off2[2];
  #pragma unroll
  for (int p = 0; p < 2; ++p) {
    int u = 32*w + p*16 + c16;
    up[p] = u;
    off2[p] = (u >> 5)*512 + (u & 31);
  }

  float cr[2] = {0.f, 0.f}, hr[2] = {0.f, 0.f};
  if (q == 0) {
    #pragma unroll
    for (int p = 0; p < 2; ++p) {
      cr[p] = wsC [row*256 + up[p]];
      hr[p] = wsHf[row*256 + up[p]];
    }
  }

  // zero plane buffers (covers pad rows 1..15 forever): 16384B / 512 thr
  ((int4*)hP)[tid]       = make_int4(0,0,0,0);
  ((int4*)hP)[tid + 512] = make_int4(0,0,0,0);
  __syncthreads();
  if (q == 0) {
    #pragma unroll
    for (int p = 0; p < 2; ++p)
      emit2(&hP[0][0][0], &hP[0][1][0], off2[p], hr[p]);
  }
  // initial gx slab (slab index tl=0 -> b4g)
  dma16((const uint8_t*)(gx + (size_t)b4g*4096) + tid*16, &gxS[0][tid*16]);
  __syncthreads();

  int cur = 0;
  int tEnd = min(tbase + tcount, li);

  for (int t = tbase; t < tEnd; ++t) {
    // stage next step's gx slab
    {
      int tn = (t + 1 < tEnd) ? (t + 1 - tbase) : (t - tbase);
      dma16((const uint8_t*)(gx + ((size_t)(tn*64 + b4g))*4096) + tid*16,
            &gxS[cur ^ 1][tid*16]);
    }

    f32x4 acc[8];
    #pragma unroll
    for (int gp = 0; gp < 8; ++gp) acc[gp] = (f32x4){0.f,0.f,0.f,0.f};

    // GEMM: H and L planes via MX MFMA, weights in registers.
    // scales: H-plane 2^-4 * 2^-4 (h x16, w x16); L-plane 2^-8 * 2^-4.
    #pragma unroll
    for (int kb = 0; kb < 2; ++kb) {
      int ao = ((kb*4 + q)*16 + c16)*32;
      union { int4 i[2]; i32x8 v; } aH, aL;
      aH.i[0] = *(const int4*)&hP[cur][0][ao];
      aH.i[1] = *(const int4*)&hP[cur][0][ao + 16];
      aL.i[0] = *(const int4*)&hP[cur][1][ao];
      aL.i[1] = *(const int4*)&hP[cur][1][ao + 16];
      #pragma unroll
      for (int gp = 0; gp < 8; ++gp) {
        acc[gp] = MFMA_MX(aH.v, breg[gp][kb], acc[gp], 0x7B7B7B7B, 0x7B7B7B7B);
        acc[gp] = MFMA_MX(aL.v, breg[gp][kb], acc[gp], 0x77777777, 0x7B7B7B7B);
      }
    }

    // gates + emit: row m=0 lives in q==0 lanes, elem 0; gate gd of unit
    // u=32w+p*16+c16 is acc[gd*2+p][0]. gx bias from staged slab.
    if (q == 0) {
      const uint16_t* gs = (const uint16_t*)&gxS[cur][0];
      float pre[8];
      #pragma unroll
      for (int gp = 0; gp < 8; ++gp)
        pre[gp] = acc[gp][0] + bf2f(gs[(ntg[gp]*16 + c16)*4 + rloc]);
      #pragma unroll
      for (int p = 0; p < 2; ++p) {
        float cn = sigm(pre[2 + p])*cr[p] + sigm(pre[0 + p])*tanh_(pre[4 + p]);
        float hw = sigm(pre[6 + p])*tanh_(cn);
        cr[p] = cn; hr[p] = hw;
        emit2(&hP[cur ^ 1][0][0], &hP[cur ^ 1][1][0], off2[p], hw);
      }
    }
    __syncthreads();
    cur ^= 1;
  }

  if (q == 0) {
    #pragma unroll
    for (int p = 0; p < 2; ++p) {
      wsC [row*256 + up[p]] = cr[p];
      wsHf[row*256 + up[p]] = hr[p];
    }
    if (last) {
      #pragma unroll
      for (int p = 0; p < 2; ++p)
        hn[row*256 + up[p]] = hr[p];
    }
  }
}

// ---------------------------------------------------------------------------
__global__ __launch_bounds__(256) void k_attn(
    const uint16_t* __restrict__ y, const float* __restrict__ hn,
    const uint16_t* __restrict__ linw, const uint16_t* __restrict__ linb,
    void* __restrict__ outv, const int* __restrict__ flag)
{
  __shared__ float hnS[256];
  __shared__ float attnS[512];
  int b = blockIdx.x;
  int tid = threadIdx.x, lane = tid & 63, w = tid >> 6;
  int isb = *flag;
  hnS[tid] = hn[b*256 + tid];
  __syncthreads();
  for (int t = w; t < 512; t += 4) {
    uint2 d = *(const uint2*)(y + ((size_t)b*512 + t)*256 + lane*4);
    float s = bf2f((uint16_t)(d.x & 0xffffu)) * hnS[lane*4 + 0]
            + bf2f((uint16_t)(d.x >> 16))     * hnS[lane*4 + 1]
            + bf2f((uint16_t)(d.y & 0xffffu)) * hnS[lane*4 + 2]
            + bf2f((uint16_t)(d.y >> 16))     * hnS[lane*4 + 3];
    #pragma unroll
    for (int off = 32; off >= 1; off >>= 1) s += __shfl_xor(s, off);
    if (lane == 0) attnS[t] = s * 0.0625f;     // 1/sqrt(256)
  }
  __syncthreads();
  float acc = 0.f;
  #pragma unroll 4
  for (int t = 0; t < 512; ++t)
    acc += attnS[t] * bf2f(y[((size_t)b*512 + t)*256 + tid]);
  if (isb) ((uint16_t*)outv)[7936 + b*256 + tid] = f2bf(acc);
  else     ((float*)outv)[7936 + b*256 + tid] = acc;
  if (tid < 31) {
    float a2 = bf2f(linb[tid]);
    for (int k = 0; k < 256; ++k) a2 += hnS[k] * bf2f(linw[tid*256 + k]);
    if (isb) ((uint16_t*)outv)[b*31 + tid] = f2bf(a2);
    else     ((float*)outv)[b*31 + tid] = a2;
  }
}

// ---------------------------------------------------------------------------
extern "C" void kernel_launch(void* const* d_in, const int* in_sizes, int n_in,
                              void* d_out, int out_size, void* d_ws, size_t ws_size,
                              hipStream_t stream)
{
  (void)in_sizes; (void)out_size;
  if (n_in < 15) return;
  const int* x   = (const int*)d_in[0];
  const int* len = (const int*)d_in[1];

  uint8_t* p = (uint8_t*)d_ws;
  auto take = [&](size_t n){ uint8_t* r = p; p += (n + 255) & ~(size_t)255; return r; };
  int*      flag  = (int*)take(256);
  uint16_t* c1bC  = (uint16_t*)take(256);
  uint16_t* c2bC  = (uint16_t*)take(256);
  uint16_t* bngC  = (uint16_t*)take(512);
  uint16_t* bnbC  = (uint16_t*)take(512);
  uint16_t* bihC  = (uint16_t*)take(2048);
  uint16_t* bhhC  = (uint16_t*)take(2048);
  uint16_t* linwC = (uint16_t*)take(15872);
  uint16_t* linbC = (uint16_t*)take(64);
  uint16_t* fragC = (uint16_t*)take(327680);
  uint16_t* fragI = (uint16_t*)take(524288);
  uint2*    fragH8= (uint2*)take(262144);
  float*    bnbuf = (float*)take(4096);
  float*    wsHf  = (float*)take(262144);
  float*    wsC   = (float*)take(262144);
  float*    hnbuf = (float*)take(262144);
  uint16_t* y     = (uint16_t*)take(67108864ull);

  // gxb: 256MB (single-chunk, all 512 t) if workspace allows, else 64MB
  // (4-chunk). Host-side branch only; kernels are identical.
  size_t prefix = (size_t)(p - (uint8_t*)d_ws);
  bool big = (prefix + 268435456ull) <= ws_size;
  uint16_t* gxb = (uint16_t*)take(big ? 268435456ull : 67108864ull);
  if ((size_t)(p - (uint8_t*)d_ws) > ws_size) return;

  // big converted tensors live inside gxb (dead before k_gx first writes it)
  uint16_t* etabC = gxb;
  uint16_t* c1wC  = (uint16_t*)((uint8_t*)gxb + 16u*1024*1024);
  uint16_t* c2wC  = (uint16_t*)((uint8_t*)gxb + 17u*1024*1024);
  uint16_t* wihC  = (uint16_t*)((uint8_t*)gxb + 18u*1024*1024);
  uint16_t* whhC  = (uint16_t*)((uint8_t*)gxb + 19u*1024*1024);

  k_sniff<<<1, 256, 0, stream>>>((const uint32_t*)d_in[2], flag);

  CvtArgs A;
  int c0 = 0;
  auto put = [&](int i, const void* s, uint16_t* d, int n){
    A.a[i].s = s; A.a[i].d = d; A.a[i].n = n; A.a[i].c0 = c0;
    c0 += (n + 4095) / 4096;
  };
  put(0,  d_in[2],  etabC, 6400000);
  put(1,  d_in[3],  c1wC,  49152);
  put(2,  d_in[4],  c1bC,  128);
  put(3,  d_in[5],  c2wC,  81920);
  put(4,  d_in[6],  c2bC,  128);
  put(5,  d_in[7],  bngC,  256);
  put(6,  d_in[8],  bnbC,  256);
  put(7,  d_in[9],  wihC,  262144);
  put(8,  d_in[10], whhC,  262144);
  put(9,  d_in[11], bihC,  1024);
  put(10, d_in[12], bhhC,  1024);
  put(11, d_in[13], linwC, 7936);
  put(12, d_in[14], linbC, 31);
  k_cvt<<<c0, 256, 0, stream>>>(A, flag);

  k_prep<<<512, 256, 0, stream>>>(c1wC, c2wC, wihC, whhC, fragC, fragI, fragH8,
                                  bnbuf, wsHf, wsC);
  k_conv<<<2048, 256, 0, stream>>>(x, etabC, fragC, c1bC, c2bC, y, bnbuf);
  k_bn<<<1, 256, 0, stream>>>(bngC, bnbC, bnbuf);
  if (big) {
    // one gx pass over all 512 timesteps, one 512-step lstm launch
    k_gx<<<dim3(2048, 4), 256, 0, stream>>>(y, bnbuf, fragI, bihC, bhhC, gxb, 0);
    k_lstm<<<256, 512, 0, stream>>>(gxb, fragH8, len, wsHf, wsC, hnbuf,
                                    0, 512, 1);
  } else {
    for (int c = 0; c < 4; ++c) {
      k_gx<<<dim3(512, 4), 256, 0, stream>>>(y, bnbuf, fragI, bihC, bhhC, gxb, c*128);
      k_lstm<<<256, 512, 0, stream>>>(gxb, fragH8, len, wsHf, wsC, hnbuf,
                                      c*128, 128, (c == 3) ? 1 : 0);
    }
  }
  k_attn<<<256, 256, 0, stream>>>(y, hnbuf, linwC, linbC, d_out, flag);
}